// Round 6
// baseline (84.553 us; speedup 1.0000x reference)
//
#include <hip/hip_runtime.h>

// INT8QuantizedLinear: B=16, S=512, IN=1024, OUT=4096  (M=8192, N=4096, K=1024)
// Harness widens integer inputs: weight arrives as const int* (int32 per value).
// Round 6: faithful m201-style phase schedule for i8. 256x256 tile, 8 waves,
// BK=64, 16 K-tiles, 4 quadrant-phases/tile. Per phase: vmcnt(2); s_barrier;
// compiler-scheduled ds_reads (NO asm lgkmcnt, NO sched_barrier); 1 half-tile
// stage; setprio-wrapped 8 MFMA. vmcnt never 0 in main loop; prologue stages
// tile 0's half-tiles in consumption order {Ah0,Bh0,Bh1,Ah1}.

#define M_TOT 8192
#define N_TOT 4096
#define K_TOT 1024
#define QMAXF 127.0f

#define BM 256
#define BN 256
#define BK 64               // i8 elems per LDS K-tile (64 B rows)
#define NKT (K_TOT / BK)    // 16

typedef int i32x4 __attribute__((ext_vector_type(4)));

// ---------------------------------------------------------------------------
// Kernel 0: fused prep (quant blocks [0,8192), weight repack [8192,12288))
// ---------------------------------------------------------------------------
__global__ __launch_bounds__(256) void prep(const float* __restrict__ x,
                                            const int* __restrict__ w32,
                                            signed char* __restrict__ xq,
                                            signed char* __restrict__ w8,
                                            float* __restrict__ iscale) {
  const int b = blockIdx.x;
  const int t = threadIdx.x;

  if (b < M_TOT) {
    const float4 v = reinterpret_cast<const float4*>(x)[(size_t)b * 256 + t];
    float m = fmaxf(fmaxf(fabsf(v.x), fabsf(v.y)), fmaxf(fabsf(v.z), fabsf(v.w)));
#pragma unroll
    for (int off = 32; off >= 1; off >>= 1) m = fmaxf(m, __shfl_xor(m, off, 64));

    __shared__ float wmax[4];
    const int lane = t & 63, wid = t >> 6;
    if (lane == 0) wmax[wid] = m;
    __syncthreads();
    const float amax = fmaxf(fmaxf(wmax[0], wmax[1]), fmaxf(wmax[2], wmax[3]));

    float scale = amax / QMAXF;
    if (scale == 0.0f) scale = 1.0f;

    int qi;
    signed char* qb = reinterpret_cast<signed char*>(&qi);
    qb[0] = (signed char)(int)fminf(fmaxf(rintf(v.x / scale), -128.0f), 127.0f);
    qb[1] = (signed char)(int)fminf(fmaxf(rintf(v.y / scale), -128.0f), 127.0f);
    qb[2] = (signed char)(int)fminf(fmaxf(rintf(v.z / scale), -128.0f), 127.0f);
    qb[3] = (signed char)(int)fminf(fmaxf(rintf(v.w / scale), -128.0f), 127.0f);
    reinterpret_cast<int*>(xq)[(size_t)b * 256 + t] = qi;

    if (t == 0) iscale[b] = scale;
  } else {
    const int i = (b - M_TOT) * 256 + t;
    const int4 v = reinterpret_cast<const int4*>(w32)[i];
    const int packed = (v.x & 0xFF) | ((v.y & 0xFF) << 8) |
                       ((v.z & 0xFF) << 16) | (v.w << 24);
    reinterpret_cast<int*>(w8)[i] = packed;
  }
}

// ---------------------------------------------------------------------------
__device__ __forceinline__ void gload_lds16(const void* g, void* l) {
  __builtin_amdgcn_global_load_lds(
      (const __attribute__((address_space(1))) unsigned int*)g,
      (__attribute__((address_space(3))) unsigned int*)l, 16, 0, 0);
}

// 8-MFMA cluster for quadrant (h = m-half, nh = n-half); a[] holds Ah_h frags
#define MFMA8(h, nh)                                                          \
  __builtin_amdgcn_s_setprio(1);                                              \
  _Pragma("unroll") for (int j = 0; j < 4; ++j)                               \
  _Pragma("unroll") for (int jb = 0; jb < 2; ++jb)                            \
      acc[(h) * 4 + j][(nh) * 2 + jb] = __builtin_amdgcn_mfma_i32_16x16x64_i8( \
          a[j], bb[(nh) * 2 + jb], acc[(h) * 4 + j][(nh) * 2 + jb], 0, 0, 0); \
  __builtin_amdgcn_s_setprio(0);

// One K-tile U (buf c): 4 phases. Stage order into buf c^1: Ah0,Bh0,Bh1,Ah1
// (= consumption order of tile U+1). VM* are vmcnt immediates (strings).
#define TILE(U, DO_STAGE, VM0, VM1, VM2)                                      \
  {                                                                           \
    const int c = (U) & 1;                                                    \
    /* P0: quadrant (0,0) — needs Ah0,Bh0 of U */                             \
    asm volatile("s_waitcnt vmcnt(" VM0 ")" ::: "memory");                    \
    __builtin_amdgcn_s_barrier();                                             \
    _Pragma("unroll") for (int j = 0; j < 4; ++j) a[j] = rdA(c, j);           \
    bb[0] = rdB(c, 0); bb[1] = rdB(c, 1);                                     \
    if (DO_STAGE) stA(c ^ 1, (U) + 1, 0);                                     \
    MFMA8(0, 0)                                                               \
    /* P1: quadrant (0,1) — needs Bh1 of U */                                 \
    asm volatile("s_waitcnt vmcnt(" VM1 ")" ::: "memory");                    \
    __builtin_amdgcn_s_barrier();                                             \
    bb[2] = rdB(c, 2); bb[3] = rdB(c, 3);                                     \
    if (DO_STAGE) stB(c ^ 1, (U) + 1, 0);                                     \
    MFMA8(0, 1)                                                               \
    /* P2: quadrant (1,0) — needs Ah1 of U */                                 \
    asm volatile("s_waitcnt vmcnt(" VM2 ")" ::: "memory");                    \
    __builtin_amdgcn_s_barrier();                                             \
    _Pragma("unroll") for (int j = 0; j < 4; ++j) a[j] = rdA(c, 4 + j);       \
    if (DO_STAGE) stB(c ^ 1, (U) + 1, 1);                                     \
    MFMA8(1, 0)                                                               \
    /* P3: quadrant (1,1) — registers only, no barrier */                     \
    if (DO_STAGE) stA(c ^ 1, (U) + 1, 1);                                     \
    MFMA8(1, 1)                                                               \
  }

__global__ __launch_bounds__(512, 2) void int8_gemm(const signed char* __restrict__ xq,
                                                    const signed char* __restrict__ w,
                                                    const float* __restrict__ iscale,
                                                    const float* __restrict__ wscale,
                                                    const float* __restrict__ bias,
                                                    float* __restrict__ out) {
  __shared__ __attribute__((aligned(16))) signed char As[2][BM][BK];  // 32 KiB
  __shared__ __attribute__((aligned(16))) signed char Bs[2][BN][BK];  // 32 KiB

  const int t = threadIdx.x;
  const int lane = t & 63;
  const int wid = t >> 6;   // 0..7
  const int wm = wid >> 2;  // 0..1
  const int wn = wid & 3;   // 0..3

  // XCD chunking: per XCD 8 m-tiles x 8 n-tiles -> A 2MB + B 2MB in L2
  const int bid = blockIdx.x;
  const int xcd = bid & 7, li = bid >> 3;
  const int mt = (xcd >> 1) * 8 + (li >> 3);
  const int nt = (xcd & 1) * 8 + (li & 7);
  const int m0 = mt * BM, n0 = nt * BN;

  // staging: one call = 512 thr x 16 B = 8 KB = 128 rows of 64 B (half-tile).
  // Involution swizzle for 64B rows: byte ^= ((row>>1)&3)<<4.
  const int srow = t >> 2;                                        // 0..127
  const int scol_swz = ((t & 3) * 16) ^ (((srow >> 1) & 3) << 4); // source col

  auto stA = [&](int buf, int kt, int h) {
    gload_lds16(xq + (size_t)(m0 + h * 128 + srow) * K_TOT + kt * BK + scol_swz,
                &As[buf][h * 128][0] + t * 16);
  };
  auto stB = [&](int buf, int kt, int h) {
    gload_lds16(w + (size_t)(n0 + h * 128 + srow) * K_TOT + kt * BK + scol_swz,
                &Bs[buf][h * 128][0] + t * 16);
  };

  // fragment reads; interleaved mapping: m-frag f -> rows f*32 + wm*16,
  // n-frag g -> rows g*64 + wn*16. Per-lane col constant: kq ^ ((lr>>1&3)<<4).
  const int lr = lane & 15;
  const int rcol = (((lane >> 4) * 16)) ^ (((lr >> 1) & 3) << 4);
  auto rdA = [&](int buf, int f) -> i32x4 {
    return *reinterpret_cast<const i32x4*>(&As[buf][f * 32 + wm * 16 + lr][rcol]);
  };
  auto rdB = [&](int buf, int g) -> i32x4 {
    return *reinterpret_cast<const i32x4*>(&Bs[buf][g * 64 + wn * 16 + lr][rcol]);
  };

  i32x4 acc[8][4] = {};
  i32x4 a[4], bb[4];

  // prologue: tile 0's half-tiles in consumption order
  stA(0, 0, 0);  // Ah0(0)
  stB(0, 0, 0);  // Bh0(0)
  stB(0, 0, 1);  // Bh1(0)
  stA(0, 0, 1);  // Ah1(0)

  for (int U = 0; U < NKT - 1; ++U) {
    TILE(U, 1, "2", "2", "2")
  }
  TILE(NKT - 1, 0, "2", "1", "0")

  // ---- epilogue (numerically validated R5): col=lane&15, row=(lane>>4)*4+i ----
  const int col = lane & 15;
  const int rq = lane >> 4;
  float wsc[4], bv[4];
#pragma unroll
  for (int g = 0; g < 4; ++g) {
    const int gn = n0 + g * 64 + wn * 16 + col;
    wsc[g] = wscale[gn];
    bv[g] = bias[gn];
  }
#pragma unroll
  for (int f = 0; f < 8; ++f) {
    const int gmb = m0 + f * 32 + wm * 16 + rq * 4;
#pragma unroll
    for (int i = 0; i < 4; ++i) {
      const int gm = gmb + i;
      const float isc = iscale[gm];
      float* rowp = out + (size_t)gm * N_TOT + n0 + wn * 16 + col;
#pragma unroll
      for (int g = 0; g < 4; ++g)
        __builtin_nontemporal_store((float)acc[f][g][i] * wsc[g] * isc + bv[g],
                                    rowp + g * 64);
    }
  }
}

// ---------------------------------------------------------------------------
extern "C" void kernel_launch(void* const* d_in, const int* in_sizes, int n_in,
                              void* d_out, int out_size, void* d_ws, size_t ws_size,
                              hipStream_t stream) {
  const float* x = (const float*)d_in[0];
  const int* w32 = (const int*)d_in[1];
  const float* wscale = (const float*)d_in[2];
  const float* bias = (const float*)d_in[3];
  float* out = (float*)d_out;

  signed char* xq = (signed char*)d_ws;                                    // 8 MB
  float* iscale = (float*)((char*)d_ws + (size_t)M_TOT * K_TOT);           // 32 KB
  signed char* w8 = (signed char*)((char*)d_ws + (size_t)M_TOT * K_TOT + M_TOT * 4);  // 4 MB

  const int pack_blocks = (N_TOT * K_TOT / 4) / 256;
  prep<<<M_TOT + pack_blocks, 256, 0, stream>>>(x, w32, xq, w8, iscale);
  int8_gemm<<<dim3((M_TOT / BM) * (N_TOT / BN)), 512, 0, stream>>>(xq, w8, iscale, wscale, bias, out);
}